// Round 10
// baseline (23.453 us; speedup 1.0000x reference)
//
#include <hip/hip_runtime.h>

// Triple softmax along keys == uniform(1/S) to ~1e-7, so
//   out[b,s,:] = ((mean_s' v[b,s',:]) @ Wv.T + bv) @ Wo.T + bo
// independent of q, k, Wq, Wk, padding_mask, s. Measured absmax 2.4e-4
// (threshold 2.34e-3) rounds 1-9.
//
// Round 10: R9 (20.6us, 4 dispatches) -> 3 dispatches. Tail fusion retried
// with R8's two failure modes fixed: (a) reg-staged t + single syncthreads
// (R8: LDS stage + 2 barriers), (b) write grid 1024 blocks / 16KB each
// (R8: 256 blk / 64KB). 16x Wo re-reads (64 MB) are L2-resident per XCD;
// HBM fetch unchanged. Identical op order per replica -> deterministic.
//   KA colsum single-pass (256 blk, line-aligned col slices)
//   KB t = vmean@Wv.T + bv (256 blk, reg-staged, folds halves+1/SEQ)
//   KE r = t@Wo.T + bo + broadcast (grid (64,16)=1024 blk)

#define BATCH 4
#define SEQ 1024
#define DIM 1024
#define D4 256            // float4 per row

typedef float f32x4 __attribute__((ext_vector_type(4)));

// ---- KA: partial[half][b][col] = sum of 512 rows. grid (4,32,2), 256 thr ----
__global__ void __launch_bounds__(256) ka_colsum(const f32x4* __restrict__ v4,
                                                 f32x4* __restrict__ partial) {
    __shared__ f32x4 sh[32][8];
    const int b = blockIdx.x, cq = blockIdx.y, half = blockIdx.z;
    const int c = threadIdx.x & 7, r = threadIdx.x >> 3;
    const int col = cq * 8 + c;
    const f32x4* p = v4 + (size_t)(b * SEQ + half * 512 + r) * D4 + col;
    f32x4 s = {0.f, 0.f, 0.f, 0.f};
#pragma unroll
    for (int i = 0; i < 16; ++i)
        s += __builtin_nontemporal_load(p + (size_t)(32 * i) * D4);
    sh[r][c] = s;
    __syncthreads();
#pragma unroll
    for (int st = 16; st > 0; st >>= 1) {
        if (r < st) sh[r][c] += sh[r + st][c];
        __syncthreads();
    }
    if (r == 0)
        partial[(size_t)(half * BATCH + b) * D4 + col] = sh[0][c];
}

// ---- KB: t[b][n] = bv[n] + ((h0+h1)/SEQ)·Wv[n]. grid 256, 256 thr ----
__global__ void __launch_bounds__(256) kb_matvec1(const f32x4* __restrict__ partial,
                                                  const f32x4* __restrict__ W4,
                                                  const float* __restrict__ bias,
                                                  float* __restrict__ y) {
    const int wv = threadIdx.x >> 6, lane = threadIdx.x & 63;
    const int n = blockIdx.x * 4 + wv;
    const f32x4* wrow = W4 + (size_t)n * D4;
    const float inv = 1.0f / SEQ;

    f32x4 w[4], xv[4][4];
#pragma unroll
    for (int it = 0; it < 4; ++it) {
        const int col = it * 64 + lane;
        w[it] = __builtin_nontemporal_load(wrow + col);
#pragma unroll
        for (int bb = 0; bb < 4; ++bb)
            xv[bb][it] = (partial[(size_t)bb * D4 + col]
                        + partial[(size_t)(BATCH + bb) * D4 + col]) * inv;
    }

    float a0 = 0.f, a1 = 0.f, a2 = 0.f, a3 = 0.f;
#pragma unroll
    for (int it = 0; it < 4; ++it) {
        a0 += w[it].x * xv[0][it].x + w[it].y * xv[0][it].y
            + w[it].z * xv[0][it].z + w[it].w * xv[0][it].w;
        a1 += w[it].x * xv[1][it].x + w[it].y * xv[1][it].y
            + w[it].z * xv[1][it].z + w[it].w * xv[1][it].w;
        a2 += w[it].x * xv[2][it].x + w[it].y * xv[2][it].y
            + w[it].z * xv[2][it].z + w[it].w * xv[2][it].w;
        a3 += w[it].x * xv[3][it].x + w[it].y * xv[3][it].y
            + w[it].z * xv[3][it].z + w[it].w * xv[3][it].w;
    }
#pragma unroll
    for (int off = 32; off > 0; off >>= 1) {
        a0 += __shfl_down(a0, off);
        a1 += __shfl_down(a1, off);
        a2 += __shfl_down(a2, off);
        a3 += __shfl_down(a3, off);
    }
    if (lane == 0) {
        const float bb = bias[n];
        y[0 * DIM + n] = a0 + bb;
        y[1 * DIM + n] = a1 + bb;
        y[2 * DIM + n] = a2 + bb;
        y[3 * DIM + n] = a3 + bb;
    }
}

// ---- KE: fused r = t@Wo.T + bo AND broadcast. grid (64,16), 256 thr ----
// Block (nb,sc): computes r[all b][nb*16..+16) with reg-staged t (xv hoisted
// out of the row loop), one syncthreads, then writes those 16 cols (one 64B
// line per out row, 4 lanes/row) for s in [sc*64, sc*64+64). 16 KB/block.
__global__ void __launch_bounds__(256) ke_out(const f32x4* __restrict__ t4,
                                              const f32x4* __restrict__ Wo4,
                                              const float* __restrict__ bo,
                                              f32x4* __restrict__ out4) {
    __shared__ alignas(16) float shr[4][16];  // r slice for this n-chunk
    const int tid = threadIdx.x;
    const int nb  = blockIdx.x;               // 0..63 column chunk
    const int sc  = blockIdx.y;               // 0..15 s chunk
    const int wv = tid >> 6, lane = tid & 63;

    // hoisted t loads: same cols for all 4 rows this wave computes
    f32x4 xv[4][4];
#pragma unroll
    for (int it = 0; it < 4; ++it) {
        const int col = it * 64 + lane;
#pragma unroll
        for (int bb = 0; bb < 4; ++bb) xv[bb][it] = t4[bb * D4 + col];
    }

#pragma unroll
    for (int i = 0; i < 4; ++i) {
        const int nl = wv * 4 + i;            // 0..15
        const int n  = nb * 16 + nl;
        const f32x4* wrow = Wo4 + (size_t)n * D4;
        f32x4 w[4];
#pragma unroll
        for (int it = 0; it < 4; ++it) w[it] = wrow[it * 64 + lane];
        float a0 = 0.f, a1 = 0.f, a2 = 0.f, a3 = 0.f;
#pragma unroll
        for (int it = 0; it < 4; ++it) {
            a0 += w[it].x * xv[0][it].x + w[it].y * xv[0][it].y
                + w[it].z * xv[0][it].z + w[it].w * xv[0][it].w;
            a1 += w[it].x * xv[1][it].x + w[it].y * xv[1][it].y
                + w[it].z * xv[1][it].z + w[it].w * xv[1][it].w;
            a2 += w[it].x * xv[2][it].x + w[it].y * xv[2][it].y
                + w[it].z * xv[2][it].z + w[it].w * xv[2][it].w;
            a3 += w[it].x * xv[3][it].x + w[it].y * xv[3][it].y
                + w[it].z * xv[3][it].z + w[it].w * xv[3][it].w;
        }
#pragma unroll
        for (int off = 32; off > 0; off >>= 1) {
            a0 += __shfl_down(a0, off);
            a1 += __shfl_down(a1, off);
            a2 += __shfl_down(a2, off);
            a3 += __shfl_down(a3, off);
        }
        if (lane == 0) {
            const float bb = bo[n];
            shr[0][nl] = a0 + bb;
            shr[1][nl] = a1 + bb;
            shr[2][nl] = a2 + bb;
            shr[3][nl] = a3 + bb;
        }
    }
    __syncthreads();

    // write: thread = (row-group pg 0..63, f4 index f4i 0..3); 4 stores each
    const f32x4* r4 = (const f32x4*)shr;      // r4[b*4 + f4i]
    const int f4i = tid & 3, pg = tid >> 2;
    const int s = sc * 64 + pg;
    const size_t cbase = (size_t)nb * 4 + f4i;
#pragma unroll
    for (int b = 0; b < 4; ++b) {
        __builtin_nontemporal_store(r4[b * 4 + f4i],
            out4 + (size_t)(b * SEQ + s) * D4 + cbase);
    }
}

extern "C" void kernel_launch(void* const* d_in, const int* in_sizes, int n_in,
                              void* d_out, int out_size, void* d_ws, size_t ws_size,
                              hipStream_t stream) {
    const f32x4* v4  = (const f32x4*)d_in[2];
    const f32x4* Wv4 = (const f32x4*)d_in[8];
    const float* bv  = (const float*)d_in[9];
    const f32x4* Wo4 = (const f32x4*)d_in[10];
    const float* bo  = (const float*)d_in[11];
    f32x4* out4 = (f32x4*)d_out;

    float* ws = (float*)d_ws;
    f32x4* partial = (f32x4*)ws;                 // 2*4*1024 floats = 32 KB
    float* t = ws + 2 * BATCH * DIM;             // 4096 floats

    ka_colsum<<<dim3(BATCH, 32, 2), 256, 0, stream>>>(v4, partial);
    kb_matvec1<<<256, 256, 0, stream>>>(partial, Wv4, bv, t);
    ke_out<<<dim3(64, 16), 256, 0, stream>>>((const f32x4*)t, Wo4, bo, out4);
}

// Round 11
// 20.807 us; speedup vs baseline: 1.1272x; 1.1272x over previous
//
#include <hip/hip_runtime.h>

// Triple softmax along keys == uniform(1/S) to ~1e-7, so
//   out[b,s,:] = ((mean_s' v[b,s',:]) @ Wv.T + bv) @ Wo.T + bo
// independent of q, k, Wq, Wk, padding_mask, s. Measured absmax 2.4e-4
// (threshold 2.34e-3) rounds 1-10.
//
// FINAL (= round 9, measured 20.58us best): 4 dispatches, zero redundant
// traffic, every BW-bound phase >=256 blocks.
//   KA colsum single-pass (256 blk, line-aligned 128B col slices, LDS tree)
//   KB t = vmean@Wv.T + bv (256 blk, reg-staged, folds halves + 1/SEQ)
//   KC r = t@Wo.T + bo     (256 blk, reg-staged)
//   KD broadcast           (1024 blk, full-line nt stores)
// Rejected by measurement: cooperative grid.sync (~50us/sync, R3);
// tail fusion (R6/R8/R10: serial compute prologue ahead of write phase +
// 16x L2 traffic); redundant-input fusions (R2/R4: L3-bound re-reads);
// <256-block BW phases (R6). Head fusion (R9) was the last clean win.

#define BATCH 4
#define SEQ 1024
#define DIM 1024
#define D4 256            // float4 per row

typedef float f32x4 __attribute__((ext_vector_type(4)));

// ---- KA: partial[half][b][col] = sum of 512 rows. grid (4,32,2), 256 thr ----
// thread = (r 0..31, c 0..7); col = cq*8+c; rows half*512 + r + 32*i.
// Per-wave access: 8 rows x 128 B contiguous = full L2 lines.
__global__ void __launch_bounds__(256) ka_colsum(const f32x4* __restrict__ v4,
                                                 f32x4* __restrict__ partial) {
    __shared__ f32x4 sh[32][8];
    const int b = blockIdx.x, cq = blockIdx.y, half = blockIdx.z;
    const int c = threadIdx.x & 7, r = threadIdx.x >> 3;
    const int col = cq * 8 + c;
    const f32x4* p = v4 + (size_t)(b * SEQ + half * 512 + r) * D4 + col;
    f32x4 s = {0.f, 0.f, 0.f, 0.f};
#pragma unroll
    for (int i = 0; i < 16; ++i)
        s += __builtin_nontemporal_load(p + (size_t)(32 * i) * D4);
    sh[r][c] = s;
    __syncthreads();
#pragma unroll
    for (int st = 16; st > 0; st >>= 1) {
        if (r < st) sh[r][c] += sh[r + st][c];
        __syncthreads();
    }
    if (r == 0)
        partial[(size_t)(half * BATCH + b) * D4 + col] = sh[0][c];
}

// ---- KB: t[b][n] = bv[n] + ((h0+h1)/SEQ)·Wv[n]. grid 256, 256 thr ----
// wave = one Wv row x all 4 batches; x combined from halves in registers.
__global__ void __launch_bounds__(256) kb_matvec1(const f32x4* __restrict__ partial,
                                                  const f32x4* __restrict__ W4,
                                                  const float* __restrict__ bias,
                                                  float* __restrict__ y) {
    const int wv = threadIdx.x >> 6, lane = threadIdx.x & 63;
    const int n = blockIdx.x * 4 + wv;
    const f32x4* wrow = W4 + (size_t)n * D4;
    const float inv = 1.0f / SEQ;

    f32x4 w[4], xv[4][4];
#pragma unroll
    for (int it = 0; it < 4; ++it) {
        const int col = it * 64 + lane;
        w[it] = __builtin_nontemporal_load(wrow + col);
#pragma unroll
        for (int bb = 0; bb < 4; ++bb)
            xv[bb][it] = (partial[(size_t)bb * D4 + col]
                        + partial[(size_t)(BATCH + bb) * D4 + col]) * inv;
    }

    float a0 = 0.f, a1 = 0.f, a2 = 0.f, a3 = 0.f;
#pragma unroll
    for (int it = 0; it < 4; ++it) {
        a0 += w[it].x * xv[0][it].x + w[it].y * xv[0][it].y
            + w[it].z * xv[0][it].z + w[it].w * xv[0][it].w;
        a1 += w[it].x * xv[1][it].x + w[it].y * xv[1][it].y
            + w[it].z * xv[1][it].z + w[it].w * xv[1][it].w;
        a2 += w[it].x * xv[2][it].x + w[it].y * xv[2][it].y
            + w[it].z * xv[2][it].z + w[it].w * xv[2][it].w;
        a3 += w[it].x * xv[3][it].x + w[it].y * xv[3][it].y
            + w[it].z * xv[3][it].z + w[it].w * xv[3][it].w;
    }
#pragma unroll
    for (int off = 32; off > 0; off >>= 1) {
        a0 += __shfl_down(a0, off);
        a1 += __shfl_down(a1, off);
        a2 += __shfl_down(a2, off);
        a3 += __shfl_down(a3, off);
    }
    if (lane == 0) {
        const float bb = bias[n];
        y[0 * DIM + n] = a0 + bb;
        y[1 * DIM + n] = a1 + bb;
        y[2 * DIM + n] = a2 + bb;
        y[3 * DIM + n] = a3 + bb;
    }
}

// ---- KC: r[b][n] = bo[n] + t[b]·Wo[n]. grid 256, 256 thr ----
__global__ void __launch_bounds__(256) kc_matvec2(const f32x4* __restrict__ x4,
                                                  const f32x4* __restrict__ W4,
                                                  const float* __restrict__ bias,
                                                  float* __restrict__ y) {
    const int wv = threadIdx.x >> 6, lane = threadIdx.x & 63;
    const int n = blockIdx.x * 4 + wv;
    const f32x4* wrow = W4 + (size_t)n * D4;

    f32x4 w[4], xv[4][4];
#pragma unroll
    for (int it = 0; it < 4; ++it) {
        const int col = it * 64 + lane;
        w[it] = __builtin_nontemporal_load(wrow + col);
#pragma unroll
        for (int bb = 0; bb < 4; ++bb) xv[bb][it] = x4[bb * D4 + col];
    }

    float a0 = 0.f, a1 = 0.f, a2 = 0.f, a3 = 0.f;
#pragma unroll
    for (int it = 0; it < 4; ++it) {
        a0 += w[it].x * xv[0][it].x + w[it].y * xv[0][it].y
            + w[it].z * xv[0][it].z + w[it].w * xv[0][it].w;
        a1 += w[it].x * xv[1][it].x + w[it].y * xv[1][it].y
            + w[it].z * xv[1][it].z + w[it].w * xv[1][it].w;
        a2 += w[it].x * xv[2][it].x + w[it].y * xv[2][it].y
            + w[it].z * xv[2][it].z + w[it].w * xv[2][it].w;
        a3 += w[it].x * xv[3][it].x + w[it].y * xv[3][it].y
            + w[it].z * xv[3][it].z + w[it].w * xv[3][it].w;
    }
#pragma unroll
    for (int off = 32; off > 0; off >>= 1) {
        a0 += __shfl_down(a0, off);
        a1 += __shfl_down(a1, off);
        a2 += __shfl_down(a2, off);
        a3 += __shfl_down(a3, off);
    }
    if (lane == 0) {
        const float bb = bias[n];
        y[0 * DIM + n] = a0 + bb;
        y[1 * DIM + n] = a1 + bb;
        y[2 * DIM + n] = a2 + bb;
        y[3 * DIM + n] = a3 + bb;
    }
}

// ---- KD: broadcast r to out. grid (4,256)=1024 blk, 256 thr; 4 s-rows ----
__global__ void __launch_bounds__(256) kd_bcast(const f32x4* __restrict__ r4,
                                                f32x4* __restrict__ out4) {
    const int b = blockIdx.x, sch = blockIdx.y, tid = threadIdx.x;
    const f32x4 val = r4[(size_t)b * D4 + tid];
    f32x4* o = out4 + (size_t)(b * SEQ + sch * 4) * D4 + tid;
#pragma unroll
    for (int k = 0; k < 4; ++k) __builtin_nontemporal_store(val, o + k * D4);
}

extern "C" void kernel_launch(void* const* d_in, const int* in_sizes, int n_in,
                              void* d_out, int out_size, void* d_ws, size_t ws_size,
                              hipStream_t stream) {
    const f32x4* v4  = (const f32x4*)d_in[2];
    const f32x4* Wv4 = (const f32x4*)d_in[8];
    const float* bv  = (const float*)d_in[9];
    const f32x4* Wo4 = (const f32x4*)d_in[10];
    const float* bo  = (const float*)d_in[11];
    f32x4* out4 = (f32x4*)d_out;

    float* ws = (float*)d_ws;
    f32x4* partial = (f32x4*)ws;                 // 2*4*1024 floats = 32 KB
    float* t = ws + 2 * BATCH * DIM;             // 4096 floats
    float* r = t + BATCH * DIM;                  // 4096 floats

    ka_colsum<<<dim3(BATCH, 32, 2), 256, 0, stream>>>(v4, partial);
    kb_matvec1<<<256, 256, 0, stream>>>(partial, Wv4, bv, t);
    kc_matvec2<<<256, 256, 0, stream>>>((const f32x4*)t, Wo4, bo, r);
    kd_bcast<<<dim3(BATCH, 256), 256, 0, stream>>>((const f32x4*)r, out4);
}